// Round 11
// baseline (144.576 us; speedup 1.0000x reference)
//
#include <hip/hip_runtime.h>

#define D 768
#define CAP 64        // max layer-2 in-edges per target
#define MD1 16        // max in-degree per needed node (real ~2-3)
#define NSLOTMAX 1040 // B + B*CAP (B=16)
#define VROWS 64      // cap on total valid rows (real ~48)
#define NI 24         // i-chunks (768 = 24*32)
#define IC 32
#define NPROJ 768     // proj blocks in kA
#define NEG 0.2f

__device__ __forceinline__ float wave_reduce(float v) {
    #pragma unroll
    for (int o = 32; o > 0; o >>= 1) v += __shfl_down(v, o, 64);
    return v;
}

// KA: blocks [0,NPROJ): projected attention vectors; blocks [NPROJ,..): l2 edge scan
__global__ __launch_bounds__(256) void kA_proj_build(
        const float* W1, const float* We1, const float* W2, const float* We2,
        const float* al1, const float* ar1, const float* ae1,
        const float* al2, const float* ar2, const float* ae2,
        const int* __restrict__ dst, const int* __restrict__ goff,
        int E, int B, float* v, int* l2e, int* cnt) {
    int bid = blockIdx.x, tid = threadIdx.x;
    if (bid < NPROJ) {
        int task = bid * 4 + (tid >> 6);
        int lane = tid & 63;
        if (task >= 4 * D) return;
        int g = task / D, i = task % D;
        const float* W; const float* p1; const float* p2 = nullptr; int o1 = 0, o2 = 0;
        switch (g) {
            case 0: W = W1;  p1 = al1; p2 = ar1; o1 = 0;     o2 = D;     break;
            case 1: W = We1; p1 = ae1;           o1 = 2 * D;             break;
            case 2: W = W2;  p1 = al2; p2 = ar2; o1 = 3 * D; o2 = 4 * D; break;
            default:W = We2; p1 = ae2;           o1 = 5 * D;             break;
        }
        float s1 = 0.f, s2 = 0.f;
        for (int j = lane; j < D; j += 64) {
            float w = W[(long)i * D + j];
            s1 += w * p1[j];
            if (p2) s2 += w * p2[j];
        }
        #pragma unroll
        for (int o = 32; o > 0; o >>= 1) { s1 += __shfl_down(s1, o, 64); s2 += __shfl_down(s2, o, 64); }
        if (lane == 0) { v[o1 + i] = s1; if (p2) v[o2 + i] = s2; }
    } else {
        __shared__ int tg[16];
        int sb = bid - NPROJ, ns = gridDim.x - NPROJ;
        if (tid < B) tg[tid] = goff[tid];
        __syncthreads();
        for (int e = sb * 256 + tid; e < E; e += ns * 256) {
            int d = dst[e];
            for (int b = 0; b < B; ++b) {
                if (d == tg[b]) {
                    int pos = atomicAdd(&cnt[b], 1);
                    if (pos < CAP) l2e[b * CAP + pos] = e;
                }
            }
        }
    }
}

// KB: node table; er dots + h-init; match scan; out-zero; block0 writes vl
__global__ __launch_bounds__(256) void kB_match(
        const float* __restrict__ x, const float* __restrict__ ef,
        const int* __restrict__ src, const int* __restrict__ dst,
        const int* __restrict__ goff, const int* __restrict__ l2e,
        const int* __restrict__ cnt, const float* __restrict__ b1,
        const float* __restrict__ v, int E, int B, int nslot,
        int* mcnt, int* medge, int* msrc, float* erj, float* h,
        int* vlg, int* vnp, float* out) {
    __shared__ int tnode[NSLOTMAX], tslot[NSLOTMAX];
    __shared__ int tn;
    int tid = threadIdx.x;
    if (tid == 0) tn = 0;
    __syncthreads();
    for (int s = tid; s < nslot; s += 256) {
        int node = -1; bool valid = false;
        if (s < B) { node = goff[s]; valid = true; }
        else { int rb = (s - B) >> 6, i = (s - B) & 63;
               int cb = cnt[rb]; if (cb > CAP) cb = CAP;
               if (i < cb) { node = src[l2e[rb * CAP + i]]; valid = true; } }
        if (valid) { int p = atomicAdd(&tn, 1); tnode[p] = node; tslot[p] = s; }
    }
    __syncthreads();
    int M = tn;
    const float* var1 = v + D;
    int wv = tid >> 6, lane = tid & 63;
    // out-zero (one pass across grid)
    for (int i = blockIdx.x * 256 + tid; i < B * D; i += gridDim.x * 256) out[i] = 0.f;
    // er dot + h init (one wave per slot)
    {
        int s = blockIdx.x * 4 + wv;
        if (s < nslot) {
            int j = -1; bool valid = false;
            if (s < B) { j = goff[s]; valid = true; }
            else { int rb = (s - B) >> 6, i = (s - B) & 63;
                   int cb = cnt[rb]; if (cb > CAP) cb = CAP;
                   if (i < cb) { j = src[l2e[rb * CAP + i]]; valid = true; } }
            if (valid) {
                float acc = 0.f;
                for (int c = lane; c < D; c += 64) acc += x[(long)j * D + c] * var1[c];
                acc = wave_reduce(acc);
                if (lane == 0) erj[s] = acc;
                for (int c = lane; c < D; c += 64)
                    h[(long)s * D + c] = x[(long)j * D + c] + b1[c];
            }
        }
    }
    // edge scan: append matches (edge id + src)
    for (int e = blockIdx.x * 256 + tid; e < E; e += gridDim.x * 256) {
        int d = dst[e];
        for (int c = 0; c < M; ++c) {
            if (tnode[c] == d) {
                int sl = tslot[c];
                int p = atomicAdd(&mcnt[sl], 1);
                if (p < MD1) {
                    medge[sl * MD1 + p] = e;
                    msrc[sl * MD1 + p]  = src[e];
                }
            }
        }
    }
    // canonical valid-row list (deterministic ballot order), block 0 wave 0
    if (blockIdx.x == 0 && tid < 64) {
        int base = 0;
        for (int s0 = 0; s0 < nslot; s0 += 64) {
            int s = s0 + tid;
            bool valid = false;
            if (s < B) valid = true;
            else if (s < nslot) {
                int rb = (s - B) >> 6, i = (s - B) & 63;
                int cb = cnt[rb]; if (cb > CAP) cb = CAP;
                valid = i < cb;
            }
            unsigned long long mb = __ballot(valid);
            if (valid) {
                int ci = base + __popcll(mb & ((1ULL << tid) - 1));
                if (ci < VROWS) vlg[ci] = s;
            }
            base += __popcll(mb);
        }
        if (tid == 0) *vnp = base < VROWS ? base : VROWS;
    }
}

// KC: layer-1: self-computed logits (task-parallel chunk dots) + softmax +
//     single-pass stage + weight-stationary FMA + atomic h. 144 blocks.
__global__ __launch_bounds__(256) void kC_gemm1(
        const float* __restrict__ W1, const float* __restrict__ We1,
        const float* __restrict__ x, const float* __restrict__ ef,
        const int* __restrict__ mcnt, const int* __restrict__ medge,
        const int* __restrict__ msrc, const float* __restrict__ erj,
        const int* __restrict__ vlg, const int* __restrict__ vnp,
        const float* __restrict__ v, float* h) {
    int tid = threadIdx.x;
    int q = blockIdx.x % 3, iy = (blockIdx.x / 3) % NI, rh = blockIdx.x / (3 * NI);
    int col = q * 256 + tid, i0 = iy * IC;
    __shared__ int vl_s[VROWS];
    __shared__ int vn_s, snm[32];
    __shared__ float slog[32][MD1];
    __shared__ int ssrc[32][MD1], sedge[32][MD1];
    __shared__ float sgS[32][IC], sgE[32][IC];
    const float* val1 = v;
    const float* vae1 = v + 2 * D;
    if (tid == 0) vn_s = *vnp;
    if (tid < VROWS) vl_s[tid] = vlg[tid];
    for (int i = tid; i < 32 * MD1; i += 256) ((float*)slog)[i] = 0.f;
    __syncthreads();
    int vn = vn_s;
    int half = (vn + 1) >> 1;
    int r0 = rh * half, r1 = r0 + half; if (r1 > vn) r1 = vn;
    int nr = r1 - r0;
    if (tid < nr) {  // per own row: load match list, sort by edge id
        int s = vl_s[r0 + tid];
        int nm = mcnt[s]; if (nm > MD1) nm = MD1;
        snm[tid] = nm;
        for (int k = 0; k < nm; ++k) {
            sedge[tid][k] = medge[s * MD1 + k];
            ssrc[tid][k]  = msrc[s * MD1 + k];
        }
        for (int a_ = 1; a_ < nm; ++a_) {
            int ke = sedge[tid][a_], ks = ssrc[tid][a_];
            int b = a_ - 1;
            while (b >= 0 && sedge[tid][b] > ke) {
                sedge[tid][b+1] = sedge[tid][b]; ssrc[tid][b+1] = ssrc[tid][b]; --b;
            }
            sedge[tid][b+1] = ke; ssrc[tid][b+1] = ks;
        }
    }
    __syncthreads();
    // task-parallel logit dots: (row, edge, chunk-of-128)
    for (int t = tid; t < nr * MD1 * 6; t += 256) {
        int lr = t / (MD1 * 6), rem = t % (MD1 * 6), k = rem / 6, ch = rem % 6;
        if (k >= snm[lr]) continue;
        int c0 = ch * 128;
        const float* px = x + (long)ssrc[lr][k] * D + c0;
        const float* pe = ef + (long)sedge[lr][k] * D + c0;
        float acc = 0.f;
        for (int c = 0; c < 128; ++c) acc += px[c] * val1[c0 + c] + pe[c] * vae1[c0 + c];
        atomicAdd(&slog[lr][k], acc);
    }
    __syncthreads();
    if (tid < nr) {  // leaky + softmax per row
        int nm = snm[tid];
        float er = erj[vl_s[r0 + tid]], mx = -1e30f;
        for (int k = 0; k < nm; ++k) {
            float l = slog[tid][k] + er;
            l = l >= 0.f ? l : NEG * l;
            slog[tid][k] = l; mx = fmaxf(mx, l);
        }
        float sum = 0.f;
        for (int k = 0; k < nm; ++k) { float p = expf(slog[tid][k] - mx); slog[tid][k] = p; sum += p; }
        float inv = sum > 0.f ? 1.f / sum : 0.f;
        for (int k = 0; k < nm; ++k) slog[tid][k] *= inv;
    }
    __syncthreads();
    // single-pass stage: task = (local row, mat); 2*nr <= 64
    if (tid < 2 * nr) {
        int lr = tid >> 1, mat = tid & 1;
        int nm = snm[lr];
        float acc[IC];
        #pragma unroll
        for (int i = 0; i < IC; ++i) acc[i] = 0.f;
        if (mat == 0) {
            for (int k = 0; k < nm; ++k) {
                const float* p = x + (long)ssrc[lr][k] * D + i0;
                float w_ = slog[lr][k];
                #pragma unroll
                for (int i = 0; i < IC; ++i) acc[i] += w_ * p[i];
            }
            #pragma unroll
            for (int i = 0; i < IC; ++i) sgS[lr][i] = acc[i];
        } else {
            for (int k = 0; k < nm; ++k) {
                const float* p = ef + (long)sedge[lr][k] * D + i0;
                float w_ = slog[lr][k];
                #pragma unroll
                for (int i = 0; i < IC; ++i) acc[i] += w_ * p[i];
            }
            #pragma unroll
            for (int i = 0; i < IC; ++i) sgE[lr][i] = acc[i];
        }
    }
    __syncthreads();
    if (nr > 0) {
        float w[IC], we[IC];
        #pragma unroll
        for (int k = 0; k < IC; ++k) {
            w[k]  = W1[(long)(i0 + k) * D + col];
            we[k] = We1[(long)(i0 + k) * D + col];
        }
        for (int lr = 0; lr < nr; ++lr) {
            float acc = 0.f;
            #pragma unroll
            for (int k = 0; k < IC; ++k) acc += sgS[lr][k] * w[k] + sgE[lr][k] * we[k];
            atomicAdd(&h[(long)vl_s[r0 + lr] * D + col], acc);
        }
    }
}

// KE: layer-2: self-computed logits (task-parallel) + softmax + stage + FMA
//     + base term (iy==0) -> atomic out. 72 blocks.
__global__ __launch_bounds__(256) void kE_gemm2(
        const float* __restrict__ W2, const float* __restrict__ We2,
        const float* __restrict__ ef, const int* __restrict__ l2e,
        const int* __restrict__ cnt, const float* __restrict__ b2,
        const float* __restrict__ v, const float* __restrict__ h,
        float* out, int B) {
    __shared__ float slog[16][CAP], ser[16];
    __shared__ int sedge[16][CAP], spos[16][CAP], sdeg[16];
    __shared__ float sgS[16][IC], sgE[16][IC];
    int tid = threadIdx.x;
    int q = blockIdx.x % 3, iy = blockIdx.x / 3;
    int col = q * 256 + tid, i0 = iy * IC;
    const float* val2 = v + 3 * D;
    const float* var2 = v + 4 * D;
    const float* vae2 = v + 5 * D;
    for (int i = tid; i < 16 * CAP; i += 256) ((float*)slog)[i] = 0.f;
    if (tid >= 16 * CAP / 256 * 0 && tid < 16) ser[tid] = 0.f;
    if (tid < B) {  // sort l2 list (thread per target)
        int b = tid;
        int deg = cnt[b]; if (deg > CAP) deg = CAP;
        sdeg[b] = deg;
        for (int k = 0; k < deg; ++k) { sedge[b][k] = l2e[b * CAP + k]; spos[b][k] = k; }
        for (int a_ = 1; a_ < deg; ++a_) {
            int ke = sedge[b][a_], kp = spos[b][a_]; int c = a_ - 1;
            while (c >= 0 && sedge[b][c] > ke) {
                sedge[b][c+1] = sedge[b][c]; spos[b][c+1] = spos[b][c]; --c;
            }
            sedge[b][c+1] = ke; spos[b][c+1] = kp;
        }
    }
    __syncthreads();
    // er2 tasks: (target, chunk)
    for (int t = tid; t < B * 6; t += 256) {
        int b = t / 6, ch = t % 6, c0 = ch * 128;
        const float* hb = h + (long)b * D + c0;
        float acc = 0.f;
        for (int c = 0; c < 128; ++c) acc += fmaxf(hb[c], 0.f) * var2[c0 + c];
        atomicAdd(&ser[b], acc);
    }
    // edge logit tasks: (target, edge, chunk)
    for (int t = tid; t < B * CAP * 6; t += 256) {
        int b = t / (CAP * 6), rem = t % (CAP * 6), k = rem / 6, ch = rem % 6;
        if (k >= sdeg[b]) continue;
        int c0 = ch * 128;
        const float* hs = h + (long)(B + b * CAP + spos[b][k]) * D + c0;
        const float* pe = ef + (long)sedge[b][k] * D + c0;
        float acc = 0.f;
        for (int c = 0; c < 128; ++c)
            acc += fmaxf(hs[c], 0.f) * val2[c0 + c] + pe[c] * vae2[c0 + c];
        atomicAdd(&slog[b][k], acc);
    }
    __syncthreads();
    if (tid < B) {  // leaky + softmax per target
        int b = tid, deg = sdeg[b];
        float er = ser[b], mx = -1e30f;
        for (int k = 0; k < deg; ++k) {
            float l = slog[b][k] + er;
            l = l >= 0.f ? l : NEG * l;
            slog[b][k] = l; mx = fmaxf(mx, l);
        }
        float sum = 0.f;
        for (int k = 0; k < deg; ++k) { float p = expf(slog[b][k] - mx); slog[b][k] = p; sum += p; }
        float inv = sum > 0.f ? 1.f / sum : 0.f;
        for (int k = 0; k < deg; ++k) slog[b][k] *= inv;
    }
    __syncthreads();
    // single-pass stage: 2*B = 32 tasks
    if (tid < 2 * B) {
        int r = tid >> 1, mat = tid & 1;
        int deg = sdeg[r];
        float acc[IC];
        #pragma unroll
        for (int i = 0; i < IC; ++i) acc[i] = 0.f;
        if (mat == 0) {
            for (int k = 0; k < deg; ++k) {
                const float* hs = h + (long)(B + r * CAP + spos[r][k]) * D + i0;
                float w_ = slog[r][k];
                #pragma unroll
                for (int i = 0; i < IC; ++i) acc[i] += w_ * fmaxf(hs[i], 0.f);
            }
            #pragma unroll
            for (int i = 0; i < IC; ++i) sgS[r][i] = acc[i];
        } else {
            for (int k = 0; k < deg; ++k) {
                const float* p = ef + (long)sedge[r][k] * D + i0;
                float w_ = slog[r][k];
                #pragma unroll
                for (int i = 0; i < IC; ++i) acc[i] += w_ * p[i];
            }
            #pragma unroll
            for (int i = 0; i < IC; ++i) sgE[r][i] = acc[i];
        }
    }
    __syncthreads();
    {
        float w[IC], we[IC];
        #pragma unroll
        for (int k = 0; k < IC; ++k) {
            w[k]  = W2[(long)(i0 + k) * D + col];
            we[k] = We2[(long)(i0 + k) * D + col];
        }
        for (int r = 0; r < B; ++r) {
            float acc = (iy == 0) ? fmaxf(h[(long)r * D + col], 0.f) + b2[col] : 0.f;
            #pragma unroll
            for (int k = 0; k < IC; ++k) acc += sgS[r][k] * w[k] + sgE[r][k] * we[k];
            atomicAdd(&out[(long)r * D + col], acc);
        }
    }
}

extern "C" void kernel_launch(void* const* d_in, const int* in_sizes, int n_in,
                              void* d_out, int out_size, void* d_ws, size_t ws_size,
                              hipStream_t stream) {
    const float* x    = (const float*)d_in[0];
    const float* ef   = (const float*)d_in[1];
    const int*   src  = (const int*)d_in[2];
    const int*   dst  = (const int*)d_in[3];
    const int*   goff = (const int*)d_in[4];
    const float* W1   = (const float*)d_in[5];
    const float* We1  = (const float*)d_in[6];
    const float* al1  = (const float*)d_in[7];
    const float* ar1  = (const float*)d_in[8];
    const float* ae1  = (const float*)d_in[9];
    const float* b1   = (const float*)d_in[10];
    const float* W2   = (const float*)d_in[11];
    const float* We2  = (const float*)d_in[12];
    const float* al2  = (const float*)d_in[13];
    const float* ar2  = (const float*)d_in[14];
    const float* ae2  = (const float*)d_in[15];
    const float* b2   = (const float*)d_in[16];
    float* out = (float*)d_out;

    int E = in_sizes[2];
    int B = in_sizes[4];
    int nslot = B + B * CAP;   // 1040

    float* ws    = (float*)d_ws;
    float* v     = ws;                            // 6*D
    int*   l2e   = (int*)(v + 6 * D);             // B*CAP
    int*   cnt   = l2e + B * CAP;                 // B      } zeroed by memset
    int*   mcnt  = cnt + B;                       // nslot  }
    int*   medge = mcnt + nslot;                  // nslot*MD1
    int*   msrc  = medge + nslot * MD1;           // nslot*MD1
    float* erj   = (float*)(msrc + nslot * MD1);  // nslot
    int*   vlg   = (int*)(erj + nslot);           // VROWS
    int*   vnp   = vlg + VROWS;                   // 1
    float* h     = (float*)(vnp + 1);             // nslot*D

    int egrid = (E + 255) / 256;

    hipMemsetAsync(cnt, 0, (size_t)(B + nslot) * sizeof(int), stream);
    hipLaunchKernelGGL(kA_proj_build, dim3(NPROJ + egrid), dim3(256), 0, stream,
                       W1, We1, W2, We2, al1, ar1, ae1, al2, ar2, ae2,
                       dst, goff, E, B, v, l2e, cnt);
    hipLaunchKernelGGL(kB_match, dim3(egrid), dim3(256), 0, stream,
                       x, ef, src, dst, goff, l2e, cnt, b1, v, E, B, nslot,
                       mcnt, medge, msrc, erj, h, vlg, vnp, out);
    hipLaunchKernelGGL(kC_gemm1, dim3(3 * NI * 2), dim3(256), 0, stream,
                       W1, We1, x, ef, mcnt, medge, msrc, erj, vlg, vnp, v, h);
    hipLaunchKernelGGL(kE_gemm2, dim3(3 * NI), dim3(256), 0, stream,
                       W2, We2, ef, l2e, cnt, b2, v, h, out, B);
}

// Round 12
// 76.153 us; speedup vs baseline: 1.8985x; 1.8985x over previous
//
#include <hip/hip_runtime.h>

#define D 768
#define CAP 64        // max layer-2 in-edges per target
#define MD1 16        // max in-degree per needed node (real ~2-3)
#define NSLOTMAX 1040 // B + B*CAP (B=16)
#define VROWS 64      // cap on total valid rows (real ~48)
#define QCAP 64       // per-block eager-dot queue (per-block matches ~0-3)
#define NI 24         // i-chunks (768 = 24*32)
#define IC 32
#define NPROJ 768     // proj blocks in kA
#define NSCAN 192     // edge-scan blocks in kA
#define NEG 0.2f

__device__ __forceinline__ float wave_reduce(float v) {
    #pragma unroll
    for (int o = 32; o > 0; o >>= 1) v += __shfl_down(v, o, 64);
    return v;
}

// KA: blocks [0,NPROJ): projected attention vectors; blocks [NPROJ,..): l2 edge scan
__global__ __launch_bounds__(256) void kA_proj_build(
        const float* W1, const float* We1, const float* W2, const float* We2,
        const float* al1, const float* ar1, const float* ae1,
        const float* al2, const float* ar2, const float* ae2,
        const int* __restrict__ dst, const int* __restrict__ goff,
        int E, int B, float* v, int* l2e, int* cnt) {
    int bid = blockIdx.x, tid = threadIdx.x;
    if (bid < NPROJ) {
        int task = bid * 4 + (tid >> 6);
        int lane = tid & 63;
        if (task >= 4 * D) return;
        int g = task / D, i = task % D;
        const float* W; const float* p1; const float* p2 = nullptr; int o1 = 0, o2 = 0;
        switch (g) {
            case 0: W = W1;  p1 = al1; p2 = ar1; o1 = 0;     o2 = D;     break;
            case 1: W = We1; p1 = ae1;           o1 = 2 * D;             break;
            case 2: W = W2;  p1 = al2; p2 = ar2; o1 = 3 * D; o2 = 4 * D; break;
            default:W = We2; p1 = ae2;           o1 = 5 * D;             break;
        }
        float s1 = 0.f, s2 = 0.f;
        for (int j = lane; j < D; j += 64) {
            float w = W[(long)i * D + j];
            s1 += w * p1[j];
            if (p2) s2 += w * p2[j];
        }
        #pragma unroll
        for (int o = 32; o > 0; o >>= 1) { s1 += __shfl_down(s1, o, 64); s2 += __shfl_down(s2, o, 64); }
        if (lane == 0) { v[o1 + i] = s1; if (p2) v[o2 + i] = s2; }
    } else {
        __shared__ int tg[16];
        int sb = bid - NPROJ, ns = gridDim.x - NPROJ;
        if (tid < B) tg[tid] = goff[tid];
        __syncthreads();
        for (int e = sb * 256 + tid; e < E; e += ns * 256) {
            int d = dst[e];
            for (int b = 0; b < B; ++b) {
                if (d == tg[b]) {
                    int pos = atomicAdd(&cnt[b], 1);
                    if (pos < CAP) l2e[b * CAP + pos] = e;
                }
            }
        }
    }
}

// KB: node table; er dots + h-init; match + eager logit dots; block0 writes vl
__global__ __launch_bounds__(256) void kB_match(
        const float* __restrict__ x, const float* __restrict__ ef,
        const int* __restrict__ src, const int* __restrict__ dst,
        const int* __restrict__ goff, const int* __restrict__ l2e,
        const int* __restrict__ cnt, const float* __restrict__ b1,
        const float* __restrict__ v, int E, int B, int nslot,
        int* mcnt, int* medge, int* msrc, float* melog, float* erj, float* h,
        int* vlg, int* vnp) {
    __shared__ int tnode[NSLOTMAX], tslot[NSLOTMAX];
    __shared__ int tn, qn;
    __shared__ int qe[QCAP], qs[QCAP], qsl[QCAP], qp[QCAP];
    int tid = threadIdx.x;
    if (tid == 0) { tn = 0; qn = 0; }
    __syncthreads();
    for (int s = tid; s < nslot; s += 256) {
        int node = -1; bool valid = false;
        if (s < B) { node = goff[s]; valid = true; }
        else { int rb = (s - B) >> 6, i = (s - B) & 63;
               int cb = cnt[rb]; if (cb > CAP) cb = CAP;
               if (i < cb) { node = src[l2e[rb * CAP + i]]; valid = true; } }
        if (valid) { int p = atomicAdd(&tn, 1); tnode[p] = node; tslot[p] = s; }
    }
    __syncthreads();
    int M = tn;
    const float* val1 = v;
    const float* var1 = v + D;
    const float* vae1 = v + 2 * D;
    int wv = tid >> 6, lane = tid & 63;
    // er dot + h init (one wave per slot; grid*4 == nslot)
    {
        int s = blockIdx.x * 4 + wv;
        if (s < nslot) {
            int j = -1; bool valid = false;
            if (s < B) { j = goff[s]; valid = true; }
            else { int rb = (s - B) >> 6, i = (s - B) & 63;
                   int cb = cnt[rb]; if (cb > CAP) cb = CAP;
                   if (i < cb) { j = src[l2e[rb * CAP + i]]; valid = true; } }
            if (valid) {
                float acc = 0.f;
                for (int c = lane; c < D; c += 64) acc += x[(long)j * D + c] * var1[c];
                acc = wave_reduce(acc);
                if (lane == 0) erj[s] = acc;
                for (int c = lane; c < D; c += 64)
                    h[(long)s * D + c] = x[(long)j * D + c] + b1[c];
            }
        }
    }
    // edge scan: append matches, queue eager dots
    for (int e = blockIdx.x * 256 + tid; e < E; e += gridDim.x * 256) {
        int d = dst[e];
        for (int c = 0; c < M; ++c) {
            if (tnode[c] == d) {
                int sl = tslot[c];
                int p = atomicAdd(&mcnt[sl], 1);
                if (p < MD1) {
                    int sr = src[e];
                    medge[sl * MD1 + p] = e;
                    msrc[sl * MD1 + p] = sr;
                    int qq = atomicAdd(&qn, 1);
                    if (qq < QCAP) { qe[qq] = e; qs[qq] = sr; qsl[qq] = sl; qp[qq] = p; }
                    else {  // rare overflow: serial dot, same value
                        float acc = 0.f;
                        for (int cc = 0; cc < D; ++cc)
                            acc += x[(long)sr * D + cc] * val1[cc] + ef[(long)e * D + cc] * vae1[cc];
                        melog[sl * MD1 + p] = acc;
                    }
                }
            }
        }
    }
    __syncthreads();
    int nq = qn; if (nq > QCAP) nq = QCAP;
    for (int m = wv; m < nq; m += 4) {
        int e = qe[m], sr = qs[m];
        float acc = 0.f;
        for (int c = lane; c < D; c += 64)
            acc += x[(long)sr * D + c] * val1[c] + ef[(long)e * D + c] * vae1[c];
        acc = wave_reduce(acc);
        if (lane == 0) melog[qsl[m] * MD1 + qp[m]] = acc;
    }
    // canonical valid-row list (deterministic ballot order), block 0 wave 0
    if (blockIdx.x == 0 && tid < 64) {
        int base = 0;
        for (int s0 = 0; s0 < nslot; s0 += 64) {
            int s = s0 + tid;
            bool valid = false;
            if (s < B) valid = true;
            else if (s < nslot) {
                int rb = (s - B) >> 6, i = (s - B) & 63;
                int cb = cnt[rb]; if (cb > CAP) cb = CAP;
                valid = i < cb;
            }
            unsigned long long mb = __ballot(valid);
            if (valid) {
                int ci = base + __popcll(mb & ((1ULL << tid) - 1));
                if (ci < VROWS) vlg[ci] = s;
            }
            base += __popcll(mb);
        }
        if (tid == 0) *vnp = base < VROWS ? base : VROWS;
    }
}

// KC: layer-1 GEMM; 2-way row split (144 blocks); single-pass stage; atomic h
__global__ __launch_bounds__(256) void kC_gemm1(
        const float* __restrict__ W1, const float* __restrict__ We1,
        const float* __restrict__ x, const float* __restrict__ ef,
        const int* __restrict__ mcnt, const int* __restrict__ medge,
        const int* __restrict__ msrc, const float* __restrict__ melog,
        const float* __restrict__ erj, const int* __restrict__ vlg,
        const int* __restrict__ vnp, float* h) {
    int tid = threadIdx.x;
    int q = blockIdx.x % 3, iy = (blockIdx.x / 3) % NI, rh = blockIdx.x / (3 * NI);
    int col = q * 256 + tid, i0 = iy * IC;
    __shared__ int vl_s[VROWS];
    __shared__ int vn_s, snm[32];
    __shared__ float smatt[32][MD1];
    __shared__ int ssrc[32][MD1], sedge[32][MD1];
    __shared__ float sgS[32][IC], sgE[32][IC];
    if (tid == 0) vn_s = *vnp;
    if (tid < VROWS) vl_s[tid] = vlg[tid];
    __syncthreads();
    int vn = vn_s;
    int half = (vn + 1) >> 1;
    int r0 = rh * half, r1 = r0 + half; if (r1 > vn) r1 = vn;
    int nr = r1 - r0;
    if (tid < nr) {  // per own row: load, sort by edge id, leaky+softmax
        int s = vl_s[r0 + tid];
        int nm = mcnt[s]; if (nm > MD1) nm = MD1;
        snm[tid] = nm;
        for (int k = 0; k < nm; ++k) {
            sedge[tid][k] = medge[s * MD1 + k];
            ssrc[tid][k]  = msrc[s * MD1 + k];
            smatt[tid][k] = melog[s * MD1 + k];
        }
        for (int a_ = 1; a_ < nm; ++a_) {
            int ke = sedge[tid][a_], ks = ssrc[tid][a_]; float kl = smatt[tid][a_];
            int b = a_ - 1;
            while (b >= 0 && sedge[tid][b] > ke) {
                sedge[tid][b+1] = sedge[tid][b]; ssrc[tid][b+1] = ssrc[tid][b];
                smatt[tid][b+1] = smatt[tid][b]; --b;
            }
            sedge[tid][b+1] = ke; ssrc[tid][b+1] = ks; smatt[tid][b+1] = kl;
        }
        float er = erj[s], mx = -1e30f;
        for (int k = 0; k < nm; ++k) {
            float l = smatt[tid][k] + er;
            l = l >= 0.f ? l : NEG * l;
            smatt[tid][k] = l; mx = fmaxf(mx, l);
        }
        float sum = 0.f;
        for (int k = 0; k < nm; ++k) { float p = expf(smatt[tid][k] - mx); smatt[tid][k] = p; sum += p; }
        float inv = 1.f / sum;
        for (int k = 0; k < nm; ++k) smatt[tid][k] *= inv;
    }
    __syncthreads();
    // single-pass stage: task t = (local row, mat); 2*nr <= 64 <= 256 threads
    if (tid < 2 * nr) {
        int lr = tid >> 1, mat = tid & 1;
        int nm = snm[lr];
        float acc[IC];
        #pragma unroll
        for (int i = 0; i < IC; ++i) acc[i] = 0.f;
        if (mat == 0) {
            for (int k = 0; k < nm; ++k) {
                const float* p = x + (long)ssrc[lr][k] * D + i0;
                float w_ = smatt[lr][k];
                #pragma unroll
                for (int i = 0; i < IC; ++i) acc[i] += w_ * p[i];
            }
            #pragma unroll
            for (int i = 0; i < IC; ++i) sgS[lr][i] = acc[i];
        } else {
            for (int k = 0; k < nm; ++k) {
                const float* p = ef + (long)sedge[lr][k] * D + i0;
                float w_ = smatt[lr][k];
                #pragma unroll
                for (int i = 0; i < IC; ++i) acc[i] += w_ * p[i];
            }
            #pragma unroll
            for (int i = 0; i < IC; ++i) sgE[lr][i] = acc[i];
        }
    }
    __syncthreads();
    if (nr > 0) {
        float w[IC], we[IC];
        #pragma unroll
        for (int k = 0; k < IC; ++k) {
            w[k]  = W1[(long)(i0 + k) * D + col];
            we[k] = We1[(long)(i0 + k) * D + col];
        }
        for (int lr = 0; lr < nr; ++lr) {
            float acc = 0.f;
            #pragma unroll
            for (int k = 0; k < IC; ++k) acc += sgS[lr][k] * w[k] + sgE[lr][k] * we[k];
            atomicAdd(&h[(long)vl_s[r0 + lr] * D + col], acc);
        }
    }
}

// KD: layer-2 logit dots on relu(h) + er2 + out-init (wave per task)
__global__ __launch_bounds__(256) void kD_l2prep(
        const float* __restrict__ ef, const int* __restrict__ l2e,
        const int* __restrict__ cnt, const float* __restrict__ b2,
        const float* __restrict__ v, const float* __restrict__ h,
        float* elog2, float* er2, float* out, int B, int nslot) {
    int wv = threadIdx.x >> 6, lane = threadIdx.x & 63;
    int t = blockIdx.x * 4 + wv;
    const float* val2 = v + 3 * D;
    const float* var2 = v + 4 * D;
    const float* vae2 = v + 5 * D;
    if (t < B) {
        float acc = 0.f;
        for (int c = lane; c < D; c += 64) acc += fmaxf(h[(long)t * D + c], 0.f) * var2[c];
        acc = wave_reduce(acc);
        if (lane == 0) er2[t] = acc;
        for (int c = lane; c < D; c += 64)
            out[(long)t * D + c] = fmaxf(h[(long)t * D + c], 0.f) + b2[c];
    } else if (t < nslot) {
        int rb = (t - B) >> 6, i = (t - B) & 63;
        int cb = cnt[rb]; if (cb > CAP) cb = CAP;
        if (i < cb) {
            int e = l2e[rb * CAP + i];
            const float* hs = h + (long)t * D;
            float acc = 0.f;
            for (int c = lane; c < D; c += 64)
                acc += fmaxf(hs[c], 0.f) * val2[c] + ef[(long)e * D + c] * vae2[c];
            acc = wave_reduce(acc);
            if (lane == 0) elog2[rb * CAP + i] = acc;
        }
    }
}

// KE: layer-2 GEMM; per-block scalar softmax, single-pass stage, atomic out
__global__ __launch_bounds__(256) void kE_gemm2(
        const float* __restrict__ W2, const float* __restrict__ We2,
        const float* __restrict__ ef, const int* __restrict__ l2e,
        const int* __restrict__ cnt, const float* __restrict__ elog2,
        const float* __restrict__ er2, const float* __restrict__ h,
        float* out, int B) {
    __shared__ float smatt[16][CAP];
    __shared__ int sedge[16][CAP], spos[16][CAP], sdeg[16];
    __shared__ float sgS[16][IC], sgE[16][IC];
    int tid = threadIdx.x;
    int q = blockIdx.x % 3, iy = blockIdx.x / 3;
    int col = q * 256 + tid, i0 = iy * IC;
    if (tid < B) {
        int b = tid;
        int deg = cnt[b]; if (deg > CAP) deg = CAP;
        sdeg[b] = deg;
        for (int k = 0; k < deg; ++k) { sedge[b][k] = l2e[b * CAP + k]; spos[b][k] = k; }
        for (int a_ = 1; a_ < deg; ++a_) {
            int ke = sedge[b][a_], kp = spos[b][a_]; int c = a_ - 1;
            while (c >= 0 && sedge[b][c] > ke) {
                sedge[b][c+1] = sedge[b][c]; spos[b][c+1] = spos[b][c]; --c;
            }
            sedge[b][c+1] = ke; spos[b][c+1] = kp;
        }
        float er = er2[b], mx = -1e30f;
        for (int k = 0; k < deg; ++k) {
            float l = elog2[b * CAP + spos[b][k]] + er;
            l = l >= 0.f ? l : NEG * l;
            smatt[b][k] = l; mx = fmaxf(mx, l);
        }
        float sum = 0.f;
        for (int k = 0; k < deg; ++k) { float p = expf(smatt[b][k] - mx); smatt[b][k] = p; sum += p; }
        float inv = sum > 0.f ? 1.f / sum : 0.f;
        for (int k = 0; k < deg; ++k) smatt[b][k] *= inv;
    }
    __syncthreads();
    // single-pass stage: 2*B = 32 tasks <= 256 threads
    if (tid < 2 * B) {
        int r = tid >> 1, mat = tid & 1;
        int deg = sdeg[r];
        float acc[IC];
        #pragma unroll
        for (int i = 0; i < IC; ++i) acc[i] = 0.f;
        if (mat == 0) {
            for (int k = 0; k < deg; ++k) {
                const float* hs = h + (long)(B + r * CAP + spos[r][k]) * D + i0;
                float w_ = smatt[r][k];
                #pragma unroll
                for (int i = 0; i < IC; ++i) acc[i] += w_ * fmaxf(hs[i], 0.f);
            }
            #pragma unroll
            for (int i = 0; i < IC; ++i) sgS[r][i] = acc[i];
        } else {
            for (int k = 0; k < deg; ++k) {
                const float* p = ef + (long)sedge[r][k] * D + i0;
                float w_ = smatt[r][k];
                #pragma unroll
                for (int i = 0; i < IC; ++i) acc[i] += w_ * p[i];
            }
            #pragma unroll
            for (int i = 0; i < IC; ++i) sgE[r][i] = acc[i];
        }
    }
    __syncthreads();
    {
        float w[IC], we[IC];
        #pragma unroll
        for (int k = 0; k < IC; ++k) {
            w[k]  = W2[(long)(i0 + k) * D + col];
            we[k] = We2[(long)(i0 + k) * D + col];
        }
        for (int r = 0; r < B; ++r) {
            float acc = 0.f;
            #pragma unroll
            for (int k = 0; k < IC; ++k) acc += sgS[r][k] * w[k] + sgE[r][k] * we[k];
            atomicAdd(&out[(long)r * D + col], acc);
        }
    }
}

extern "C" void kernel_launch(void* const* d_in, const int* in_sizes, int n_in,
                              void* d_out, int out_size, void* d_ws, size_t ws_size,
                              hipStream_t stream) {
    const float* x    = (const float*)d_in[0];
    const float* ef   = (const float*)d_in[1];
    const int*   src  = (const int*)d_in[2];
    const int*   dst  = (const int*)d_in[3];
    const int*   goff = (const int*)d_in[4];
    const float* W1   = (const float*)d_in[5];
    const float* We1  = (const float*)d_in[6];
    const float* al1  = (const float*)d_in[7];
    const float* ar1  = (const float*)d_in[8];
    const float* ae1  = (const float*)d_in[9];
    const float* b1   = (const float*)d_in[10];
    const float* W2   = (const float*)d_in[11];
    const float* We2  = (const float*)d_in[12];
    const float* al2  = (const float*)d_in[13];
    const float* ar2  = (const float*)d_in[14];
    const float* ae2  = (const float*)d_in[15];
    const float* b2   = (const float*)d_in[16];
    float* out = (float*)d_out;

    int E = in_sizes[2];
    int B = in_sizes[4];
    int nslot = B + B * CAP;   // 1040

    float* ws    = (float*)d_ws;
    float* v     = ws;                            // 6*D
    int*   l2e   = (int*)(v + 6 * D);             // B*CAP
    int*   cnt   = l2e + B * CAP;                 // B      } zeroed by memset
    int*   mcnt  = cnt + B;                       // nslot  }
    int*   medge = mcnt + nslot;                  // nslot*MD1
    int*   msrc  = medge + nslot * MD1;           // nslot*MD1
    float* melog = (float*)(msrc + nslot * MD1);  // nslot*MD1
    float* erj   = melog + nslot * MD1;           // nslot
    int*   vlg   = (int*)(erj + nslot);           // VROWS
    int*   vnp   = vlg + VROWS;                   // 1
    float* elog2 = (float*)(vnp + 1);             // B*CAP
    float* er2   = elog2 + B * CAP;               // B
    float* h     = er2 + B;                       // nslot*D

    int kbgrid = (nslot + 3) / 4;  // 260: covers er/h-init slots exactly

    hipMemsetAsync(cnt, 0, (size_t)(B + nslot) * sizeof(int), stream);
    hipLaunchKernelGGL(kA_proj_build, dim3(NPROJ + NSCAN), dim3(256), 0, stream,
                       W1, We1, W2, We2, al1, ar1, ae1, al2, ar2, ae2,
                       dst, goff, E, B, v, l2e, cnt);
    hipLaunchKernelGGL(kB_match, dim3(kbgrid), dim3(256), 0, stream,
                       x, ef, src, dst, goff, l2e, cnt, b1, v, E, B, nslot,
                       mcnt, medge, msrc, melog, erj, h, vlg, vnp);
    hipLaunchKernelGGL(kC_gemm1, dim3(3 * NI * 2), dim3(256), 0, stream,
                       W1, We1, x, ef, mcnt, medge, msrc, melog, erj, vlg, vnp, h);
    hipLaunchKernelGGL(kD_l2prep, dim3((nslot + 3) / 4), dim3(256), 0, stream,
                       ef, l2e, cnt, b2, v, h, elog2, er2, out, B, nslot);
    hipLaunchKernelGGL(kE_gemm2, dim3(3 * NI), dim3(256), 0, stream,
                       W2, We2, ef, l2e, cnt, elog2, er2, h, out, B);
}

// Round 13
// 76.072 us; speedup vs baseline: 1.9005x; 1.0011x over previous
//
#include <hip/hip_runtime.h>

#define D 768
#define CAP 64        // max layer-2 in-edges per target
#define MD1 16        // max in-degree per needed node (real ~2-3)
#define NSLOTMAX 1040 // B + B*CAP (B=16)
#define VROWS 64      // cap on total valid rows (real ~48)
#define QCAP 64       // per-block eager-dot queue (per-block matches ~0-3)
#define NI 24         // i-chunks (768 = 24*32)
#define IC 32
#define NPROJ 768     // proj blocks in kA
#define NSCAN 128     // edge-scan blocks in kA
#define BCAP 8        // per-block per-target l2 sublist cap
#define NEG 0.2f

__device__ __forceinline__ float wave_reduce(float v) {
    #pragma unroll
    for (int o = 32; o > 0; o >>= 1) v += __shfl_down(v, o, 64);
    return v;
}

// KA: blocks [0,NPROJ): projected attention vectors
//     blocks [NPROJ,..): l2 edge scan -> per-block LDS-local sublists (no zeroed globals)
//     scan block 0 additionally zeroes mcnt (used first by kB; untouched in kA)
__global__ __launch_bounds__(256) void kA_proj_build(
        const float* W1, const float* We1, const float* W2, const float* We2,
        const float* al1, const float* ar1, const float* ae1,
        const float* al2, const float* ar2, const float* ae2,
        const int* __restrict__ dst, const int* __restrict__ goff,
        int E, int B, float* v, int* blk_cnt, int* blk_edge, int* mcnt, int nslot) {
    int bid = blockIdx.x, tid = threadIdx.x;
    if (bid < NPROJ) {
        int task = bid * 4 + (tid >> 6);
        int lane = tid & 63;
        if (task >= 4 * D) return;
        int g = task / D, i = task % D;
        const float* W; const float* p1; const float* p2 = nullptr; int o1 = 0, o2 = 0;
        switch (g) {
            case 0: W = W1;  p1 = al1; p2 = ar1; o1 = 0;     o2 = D;     break;
            case 1: W = We1; p1 = ae1;           o1 = 2 * D;             break;
            case 2: W = W2;  p1 = al2; p2 = ar2; o1 = 3 * D; o2 = 4 * D; break;
            default:W = We2; p1 = ae2;           o1 = 5 * D;             break;
        }
        float s1 = 0.f, s2 = 0.f;
        for (int j = lane; j < D; j += 64) {
            float w = W[(long)i * D + j];
            s1 += w * p1[j];
            if (p2) s2 += w * p2[j];
        }
        #pragma unroll
        for (int o = 32; o > 0; o >>= 1) { s1 += __shfl_down(s1, o, 64); s2 += __shfl_down(s2, o, 64); }
        if (lane == 0) { v[o1 + i] = s1; if (p2) v[o2 + i] = s2; }
    } else {
        __shared__ int tg[16];
        __shared__ int lcnt[16];
        __shared__ int ledge[16][BCAP];
        int sb = bid - NPROJ;
        if (tid < B) { tg[tid] = goff[tid]; lcnt[tid] = 0; }
        __syncthreads();
        if (sb == 0)
            for (int i = tid; i < nslot; i += 256) mcnt[i] = 0;
        for (int e = sb * 256 + tid; e < E; e += NSCAN * 256) {
            int d = dst[e];
            for (int b = 0; b < B; ++b) {
                if (d == tg[b]) {
                    int p = atomicAdd(&lcnt[b], 1);
                    if (p < BCAP) ledge[b][p] = e;
                }
            }
        }
        __syncthreads();
        if (tid < B) {
            int n = lcnt[tid];
            blk_cnt[sb * 16 + tid] = n < BCAP ? n : BCAP;
        }
        if (tid < B * BCAP) {
            int b = tid / BCAP, k = tid % BCAP;
            int n = lcnt[b]; if (n > BCAP) n = BCAP;
            if (k < n) blk_edge[(sb * 16 + b) * BCAP + k] = ledge[b][k];
        }
    }
}

// KB: per-block merge of l2 sublists (LDS); node table; er dots + h-init;
//     match + eager logit dots; block 0 publishes l2e/cnt + valid-row list
__global__ __launch_bounds__(256) void kB_match(
        const float* __restrict__ x, const float* __restrict__ ef,
        const int* __restrict__ src, const int* __restrict__ dst,
        const int* __restrict__ goff,
        const int* __restrict__ blk_cnt, const int* __restrict__ blk_edge,
        const float* __restrict__ b1, const float* __restrict__ v,
        int E, int B, int nslot,
        int* mcnt, int* medge, int* msrc, float* melog, float* erj, float* h,
        int* vlg, int* vnp, int* l2e, int* cnt) {
    __shared__ int bcs[NSCAN][16];    // sublist counts
    __shared__ int off[NSCAN][16];    // sublist offsets
    __shared__ int l2l[16][CAP];      // merged l2 edge lists
    __shared__ int ltot[16];
    __shared__ int tnode[NSLOTMAX], tslot[NSLOTMAX];
    __shared__ int tn, qn;
    __shared__ int qe[QCAP], qs[QCAP], qsl[QCAP], qp[QCAP];
    int tid = threadIdx.x;
    if (tid == 0) { tn = 0; qn = 0; }
    for (int i = tid; i < NSCAN * 16; i += 256) ((int*)bcs)[i] = blk_cnt[i];
    __syncthreads();
    if (tid < B) {
        int run = 0;
        for (int sb = 0; sb < NSCAN; ++sb) { off[sb][tid] = run; run += bcs[sb][tid]; }
        ltot[tid] = run < CAP ? run : CAP;
    }
    __syncthreads();
    for (int i = tid; i < NSCAN * 16; i += 256) {
        int sb = i >> 4, b = i & 15;
        int n = bcs[sb][b], o = off[sb][b];
        for (int k = 0; k < n; ++k) {
            int pos = o + k;
            if (pos < CAP) l2l[b][pos] = blk_edge[i * BCAP + k];
        }
    }
    __syncthreads();
    // node/slot table from merged lists
    for (int s = tid; s < nslot; s += 256) {
        int node = -1; bool valid = false;
        if (s < B) { node = goff[s]; valid = true; }
        else { int rb = (s - B) >> 6, i = (s - B) & 63;
               if (i < ltot[rb]) { node = src[l2l[rb][i]]; valid = true; } }
        if (valid) { int p = atomicAdd(&tn, 1); tnode[p] = node; tslot[p] = s; }
    }
    __syncthreads();
    int M = tn;
    const float* val1 = v;
    const float* var1 = v + D;
    const float* vae1 = v + 2 * D;
    int wv = tid >> 6, lane = tid & 63;
    // er dot + h init (one wave per slot; grid*4 == nslot)
    {
        int s = blockIdx.x * 4 + wv;
        if (s < nslot) {
            int j = -1; bool valid = false;
            if (s < B) { j = goff[s]; valid = true; }
            else { int rb = (s - B) >> 6, i = (s - B) & 63;
                   if (i < ltot[rb]) { j = src[l2l[rb][i]]; valid = true; } }
            if (valid) {
                float acc = 0.f;
                for (int c = lane; c < D; c += 64) acc += x[(long)j * D + c] * var1[c];
                acc = wave_reduce(acc);
                if (lane == 0) erj[s] = acc;
                for (int c = lane; c < D; c += 64)
                    h[(long)s * D + c] = x[(long)j * D + c] + b1[c];
            }
        }
    }
    // edge scan: append matches, queue eager dots
    for (int e = blockIdx.x * 256 + tid; e < E; e += gridDim.x * 256) {
        int d = dst[e];
        for (int c = 0; c < M; ++c) {
            if (tnode[c] == d) {
                int sl = tslot[c];
                int p = atomicAdd(&mcnt[sl], 1);
                if (p < MD1) {
                    int sr = src[e];
                    medge[sl * MD1 + p] = e;
                    msrc[sl * MD1 + p] = sr;
                    int qq = atomicAdd(&qn, 1);
                    if (qq < QCAP) { qe[qq] = e; qs[qq] = sr; qsl[qq] = sl; qp[qq] = p; }
                    else {  // rare overflow: serial dot, same value
                        float acc = 0.f;
                        for (int cc = 0; cc < D; ++cc)
                            acc += x[(long)sr * D + cc] * val1[cc] + ef[(long)e * D + cc] * vae1[cc];
                        melog[sl * MD1 + p] = acc;
                    }
                }
            }
        }
    }
    __syncthreads();
    int nq = qn; if (nq > QCAP) nq = QCAP;
    for (int m = wv; m < nq; m += 4) {
        int e = qe[m], sr = qs[m];
        float acc = 0.f;
        for (int c = lane; c < D; c += 64)
            acc += x[(long)sr * D + c] * val1[c] + ef[(long)e * D + c] * vae1[c];
        acc = wave_reduce(acc);
        if (lane == 0) melog[qsl[m] * MD1 + qp[m]] = acc;
    }
    // block 0: publish l2e/cnt + canonical valid-row list
    if (blockIdx.x == 0) {
        if (tid < B) cnt[tid] = ltot[tid];
        for (int i = tid; i < B * CAP; i += 256) {
            int b = i >> 6, k = i & 63;
            if (k < ltot[b]) l2e[i] = l2l[b][k];
        }
        if (tid < 64) {
            int base = 0;
            for (int s0 = 0; s0 < nslot; s0 += 64) {
                int s = s0 + tid;
                bool valid = false;
                if (s < B) valid = true;
                else if (s < nslot) {
                    int rb = (s - B) >> 6, i = (s - B) & 63;
                    valid = i < ltot[rb];
                }
                unsigned long long mb = __ballot(valid);
                if (valid) {
                    int ci = base + __popcll(mb & ((1ULL << tid) - 1));
                    if (ci < VROWS) vlg[ci] = s;
                }
                base += __popcll(mb);
            }
            if (tid == 0) *vnp = base < VROWS ? base : VROWS;
        }
    }
}

// KC: layer-1 GEMM; 2-way row split (144 blocks); single-pass stage; atomic h
__global__ __launch_bounds__(256) void kC_gemm1(
        const float* __restrict__ W1, const float* __restrict__ We1,
        const float* __restrict__ x, const float* __restrict__ ef,
        const int* __restrict__ mcnt, const int* __restrict__ medge,
        const int* __restrict__ msrc, const float* __restrict__ melog,
        const float* __restrict__ erj, const int* __restrict__ vlg,
        const int* __restrict__ vnp, float* h) {
    int tid = threadIdx.x;
    int q = blockIdx.x % 3, iy = (blockIdx.x / 3) % NI, rh = blockIdx.x / (3 * NI);
    int col = q * 256 + tid, i0 = iy * IC;
    __shared__ int vl_s[VROWS];
    __shared__ int vn_s, snm[32];
    __shared__ float smatt[32][MD1];
    __shared__ int ssrc[32][MD1], sedge[32][MD1];
    __shared__ float sgS[32][IC], sgE[32][IC];
    if (tid == 0) vn_s = *vnp;
    if (tid < VROWS) vl_s[tid] = vlg[tid];
    __syncthreads();
    int vn = vn_s;
    int half = (vn + 1) >> 1;
    int r0 = rh * half, r1 = r0 + half; if (r1 > vn) r1 = vn;
    int nr = r1 - r0;
    if (tid < nr) {  // per own row: load, sort by edge id, leaky+softmax
        int s = vl_s[r0 + tid];
        int nm = mcnt[s]; if (nm > MD1) nm = MD1;
        snm[tid] = nm;
        for (int k = 0; k < nm; ++k) {
            sedge[tid][k] = medge[s * MD1 + k];
            ssrc[tid][k]  = msrc[s * MD1 + k];
            smatt[tid][k] = melog[s * MD1 + k];
        }
        for (int a_ = 1; a_ < nm; ++a_) {
            int ke = sedge[tid][a_], ks = ssrc[tid][a_]; float kl = smatt[tid][a_];
            int b = a_ - 1;
            while (b >= 0 && sedge[tid][b] > ke) {
                sedge[tid][b+1] = sedge[tid][b]; ssrc[tid][b+1] = ssrc[tid][b];
                smatt[tid][b+1] = smatt[tid][b]; --b;
            }
            sedge[tid][b+1] = ke; ssrc[tid][b+1] = ks; smatt[tid][b+1] = kl;
        }
        float er = erj[s], mx = -1e30f;
        for (int k = 0; k < nm; ++k) {
            float l = smatt[tid][k] + er;
            l = l >= 0.f ? l : NEG * l;
            smatt[tid][k] = l; mx = fmaxf(mx, l);
        }
        float sum = 0.f;
        for (int k = 0; k < nm; ++k) { float p = expf(smatt[tid][k] - mx); smatt[tid][k] = p; sum += p; }
        float inv = 1.f / sum;
        for (int k = 0; k < nm; ++k) smatt[tid][k] *= inv;
    }
    __syncthreads();
    // single-pass stage: task t = (local row, mat); 2*nr <= 64 <= 256 threads
    if (tid < 2 * nr) {
        int lr = tid >> 1, mat = tid & 1;
        int nm = snm[lr];
        float acc[IC];
        #pragma unroll
        for (int i = 0; i < IC; ++i) acc[i] = 0.f;
        if (mat == 0) {
            for (int k = 0; k < nm; ++k) {
                const float* p = x + (long)ssrc[lr][k] * D + i0;
                float w_ = smatt[lr][k];
                #pragma unroll
                for (int i = 0; i < IC; ++i) acc[i] += w_ * p[i];
            }
            #pragma unroll
            for (int i = 0; i < IC; ++i) sgS[lr][i] = acc[i];
        } else {
            for (int k = 0; k < nm; ++k) {
                const float* p = ef + (long)sedge[lr][k] * D + i0;
                float w_ = smatt[lr][k];
                #pragma unroll
                for (int i = 0; i < IC; ++i) acc[i] += w_ * p[i];
            }
            #pragma unroll
            for (int i = 0; i < IC; ++i) sgE[lr][i] = acc[i];
        }
    }
    __syncthreads();
    if (nr > 0) {
        float w[IC], we[IC];
        #pragma unroll
        for (int k = 0; k < IC; ++k) {
            w[k]  = W1[(long)(i0 + k) * D + col];
            we[k] = We1[(long)(i0 + k) * D + col];
        }
        for (int lr = 0; lr < nr; ++lr) {
            float acc = 0.f;
            #pragma unroll
            for (int k = 0; k < IC; ++k) acc += sgS[lr][k] * w[k] + sgE[lr][k] * we[k];
            atomicAdd(&h[(long)vl_s[r0 + lr] * D + col], acc);
        }
    }
}

// KD: layer-2 logit dots on relu(h) + er2 + out-init (wave per task)
__global__ __launch_bounds__(256) void kD_l2prep(
        const float* __restrict__ ef, const int* __restrict__ l2e,
        const int* __restrict__ cnt, const float* __restrict__ b2,
        const float* __restrict__ v, const float* __restrict__ h,
        float* elog2, float* er2, float* out, int B, int nslot) {
    int wv = threadIdx.x >> 6, lane = threadIdx.x & 63;
    int t = blockIdx.x * 4 + wv;
    const float* val2 = v + 3 * D;
    const float* var2 = v + 4 * D;
    const float* vae2 = v + 5 * D;
    if (t < B) {
        float acc = 0.f;
        for (int c = lane; c < D; c += 64) acc += fmaxf(h[(long)t * D + c], 0.f) * var2[c];
        acc = wave_reduce(acc);
        if (lane == 0) er2[t] = acc;
        for (int c = lane; c < D; c += 64)
            out[(long)t * D + c] = fmaxf(h[(long)t * D + c], 0.f) + b2[c];
    } else if (t < nslot) {
        int rb = (t - B) >> 6, i = (t - B) & 63;
        int cb = cnt[rb]; if (cb > CAP) cb = CAP;
        if (i < cb) {
            int e = l2e[rb * CAP + i];
            const float* hs = h + (long)t * D;
            float acc = 0.f;
            for (int c = lane; c < D; c += 64)
                acc += fmaxf(hs[c], 0.f) * val2[c] + ef[(long)e * D + c] * vae2[c];
            acc = wave_reduce(acc);
            if (lane == 0) elog2[rb * CAP + i] = acc;
        }
    }
}

// KE: layer-2 GEMM; per-block scalar softmax, single-pass stage, atomic out
__global__ __launch_bounds__(256) void kE_gemm2(
        const float* __restrict__ W2, const float* __restrict__ We2,
        const float* __restrict__ ef, const int* __restrict__ l2e,
        const int* __restrict__ cnt, const float* __restrict__ elog2,
        const float* __restrict__ er2, const float* __restrict__ h,
        float* out, int B) {
    __shared__ float smatt[16][CAP];
    __shared__ int sedge[16][CAP], spos[16][CAP], sdeg[16];
    __shared__ float sgS[16][IC], sgE[16][IC];
    int tid = threadIdx.x;
    int q = blockIdx.x % 3, iy = blockIdx.x / 3;
    int col = q * 256 + tid, i0 = iy * IC;
    if (tid < B) {
        int b = tid;
        int deg = cnt[b]; if (deg > CAP) deg = CAP;
        sdeg[b] = deg;
        for (int k = 0; k < deg; ++k) { sedge[b][k] = l2e[b * CAP + k]; spos[b][k] = k; }
        for (int a_ = 1; a_ < deg; ++a_) {
            int ke = sedge[b][a_], kp = spos[b][a_]; int c = a_ - 1;
            while (c >= 0 && sedge[b][c] > ke) {
                sedge[b][c+1] = sedge[b][c]; spos[b][c+1] = spos[b][c]; --c;
            }
            sedge[b][c+1] = ke; spos[b][c+1] = kp;
        }
        float er = er2[b], mx = -1e30f;
        for (int k = 0; k < deg; ++k) {
            float l = elog2[b * CAP + spos[b][k]] + er;
            l = l >= 0.f ? l : NEG * l;
            smatt[b][k] = l; mx = fmaxf(mx, l);
        }
        float sum = 0.f;
        for (int k = 0; k < deg; ++k) { float p = expf(smatt[b][k] - mx); smatt[b][k] = p; sum += p; }
        float inv = sum > 0.f ? 1.f / sum : 0.f;
        for (int k = 0; k < deg; ++k) smatt[b][k] *= inv;
    }
    __syncthreads();
    // single-pass stage: 2*B = 32 tasks <= 256 threads
    if (tid < 2 * B) {
        int r = tid >> 1, mat = tid & 1;
        int deg = sdeg[r];
        float acc[IC];
        #pragma unroll
        for (int i = 0; i < IC; ++i) acc[i] = 0.f;
        if (mat == 0) {
            for (int k = 0; k < deg; ++k) {
                const float* hs = h + (long)(B + r * CAP + spos[r][k]) * D + i0;
                float w_ = smatt[r][k];
                #pragma unroll
                for (int i = 0; i < IC; ++i) acc[i] += w_ * fmaxf(hs[i], 0.f);
            }
            #pragma unroll
            for (int i = 0; i < IC; ++i) sgS[r][i] = acc[i];
        } else {
            for (int k = 0; k < deg; ++k) {
                const float* p = ef + (long)sedge[r][k] * D + i0;
                float w_ = smatt[r][k];
                #pragma unroll
                for (int i = 0; i < IC; ++i) acc[i] += w_ * p[i];
            }
            #pragma unroll
            for (int i = 0; i < IC; ++i) sgE[r][i] = acc[i];
        }
    }
    __syncthreads();
    {
        float w[IC], we[IC];
        #pragma unroll
        for (int k = 0; k < IC; ++k) {
            w[k]  = W2[(long)(i0 + k) * D + col];
            we[k] = We2[(long)(i0 + k) * D + col];
        }
        for (int r = 0; r < B; ++r) {
            float acc = 0.f;
            #pragma unroll
            for (int k = 0; k < IC; ++k) acc += sgS[r][k] * w[k] + sgE[r][k] * we[k];
            atomicAdd(&out[(long)r * D + col], acc);
        }
    }
}

extern "C" void kernel_launch(void* const* d_in, const int* in_sizes, int n_in,
                              void* d_out, int out_size, void* d_ws, size_t ws_size,
                              hipStream_t stream) {
    const float* x    = (const float*)d_in[0];
    const float* ef   = (const float*)d_in[1];
    const int*   src  = (const int*)d_in[2];
    const int*   dst  = (const int*)d_in[3];
    const int*   goff = (const int*)d_in[4];
    const float* W1   = (const float*)d_in[5];
    const float* We1  = (const float*)d_in[6];
    const float* al1  = (const float*)d_in[7];
    const float* ar1  = (const float*)d_in[8];
    const float* ae1  = (const float*)d_in[9];
    const float* b1   = (const float*)d_in[10];
    const float* W2   = (const float*)d_in[11];
    const float* We2  = (const float*)d_in[12];
    const float* al2  = (const float*)d_in[13];
    const float* ar2  = (const float*)d_in[14];
    const float* ae2  = (const float*)d_in[15];
    const float* b2   = (const float*)d_in[16];
    float* out = (float*)d_out;

    int E = in_sizes[2];
    int B = in_sizes[4];
    int nslot = B + B * CAP;   // 1040

    float* ws      = (float*)d_ws;
    float* v       = ws;                              // 6*D
    int*   blk_cnt = (int*)(v + 6 * D);               // NSCAN*16
    int*   blk_edge= blk_cnt + NSCAN * 16;            // NSCAN*16*BCAP
    int*   l2e     = blk_edge + NSCAN * 16 * BCAP;    // B*CAP
    int*   cnt     = l2e + B * CAP;                   // B
    int*   mcnt    = cnt + B;                         // nslot (zeroed inside kA)
    int*   medge   = mcnt + nslot;                    // nslot*MD1
    int*   msrc    = medge + nslot * MD1;             // nslot*MD1
    float* melog   = (float*)(msrc + nslot * MD1);    // nslot*MD1
    float* erj     = melog + nslot * MD1;             // nslot
    int*   vlg     = (int*)(erj + nslot);             // VROWS
    int*   vnp     = vlg + VROWS;                     // 1
    float* elog2   = (float*)(vnp + 1);               // B*CAP
    float* er2     = elog2 + B * CAP;                 // B
    float* h       = er2 + B;                         // nslot*D

    int kbgrid = (nslot + 3) / 4;  // 260: covers er/h-init slots exactly

    hipLaunchKernelGGL(kA_proj_build, dim3(NPROJ + NSCAN), dim3(256), 0, stream,
                       W1, We1, W2, We2, al1, ar1, ae1, al2, ar2, ae2,
                       dst, goff, E, B, v, blk_cnt, blk_edge, mcnt, nslot);
    hipLaunchKernelGGL(kB_match, dim3(kbgrid), dim3(256), 0, stream,
                       x, ef, src, dst, goff, blk_cnt, blk_edge, b1, v, E, B, nslot,
                       mcnt, medge, msrc, melog, erj, h, vlg, vnp, l2e, cnt);
    hipLaunchKernelGGL(kC_gemm1, dim3(3 * NI * 2), dim3(256), 0, stream,
                       W1, We1, x, ef, mcnt, medge, msrc, melog, erj, vlg, vnp, h);
    hipLaunchKernelGGL(kD_l2prep, dim3((nslot + 3) / 4), dim3(256), 0, stream,
                       ef, l2e, cnt, b2, v, h, elog2, er2, out, B, nslot);
    hipLaunchKernelGGL(kE_gemm2, dim3(3 * NI), dim3(256), 0, stream,
                       W2, We2, ef, l2e, cnt, elog2, er2, h, out, B);
}

// Round 14
// 72.643 us; speedup vs baseline: 1.9902x; 1.0472x over previous
//
#include <hip/hip_runtime.h>

#define D 768
#define CAP 64        // max layer-2 in-edges per target
#define MD1 16        // max in-degree per needed node (real ~2-3)
#define NSLOTMAX 1040 // B + B*CAP (B=16)
#define VROWS 64      // cap on total valid rows (real ~48)
#define QCAP 64       // per-block eager-dot queue
#define NI 24         // i-chunks (768 = 24*32)
#define IC 32
#define NPROJ 768     // proj blocks in kA
#define NEG 0.2f

__device__ __forceinline__ float wave_reduce(float v) {
    #pragma unroll
    for (int o = 32; o > 0; o >>= 1) v += __shfl_down(v, o, 64);
    return v;
}

// KA: blocks [0,NPROJ): projected attention vectors; blocks [NPROJ,..): l2 edge scan
__global__ __launch_bounds__(256) void kA_proj_build(
        const float* W1, const float* We1, const float* W2, const float* We2,
        const float* al1, const float* ar1, const float* ae1,
        const float* al2, const float* ar2, const float* ae2,
        const int* __restrict__ dst, const int* __restrict__ goff,
        int E, int B, float* v, int* l2e, int* cnt) {
    int bid = blockIdx.x, tid = threadIdx.x;
    if (bid < NPROJ) {
        int task = bid * 4 + (tid >> 6);
        int lane = tid & 63;
        if (task >= 4 * D) return;
        int g = task / D, i = task % D;
        const float* W; const float* p1; const float* p2 = nullptr; int o1 = 0, o2 = 0;
        switch (g) {
            case 0: W = W1;  p1 = al1; p2 = ar1; o1 = 0;     o2 = D;     break;
            case 1: W = We1; p1 = ae1;           o1 = 2 * D;             break;
            case 2: W = W2;  p1 = al2; p2 = ar2; o1 = 3 * D; o2 = 4 * D; break;
            default:W = We2; p1 = ae2;           o1 = 5 * D;             break;
        }
        float s1 = 0.f, s2 = 0.f;
        for (int j = lane; j < D; j += 64) {
            float w = W[(long)i * D + j];
            s1 += w * p1[j];
            if (p2) s2 += w * p2[j];
        }
        #pragma unroll
        for (int o = 32; o > 0; o >>= 1) { s1 += __shfl_down(s1, o, 64); s2 += __shfl_down(s2, o, 64); }
        if (lane == 0) { v[o1 + i] = s1; if (p2) v[o2 + i] = s2; }
    } else {
        __shared__ int tg[16];
        int sb = bid - NPROJ, ns = gridDim.x - NPROJ;
        if (tid < B) tg[tid] = goff[tid];
        __syncthreads();
        for (int e = sb * 256 + tid; e < E; e += ns * 256) {
            int d = dst[e];
            for (int b = 0; b < B; ++b) {
                if (d == tg[b]) {
                    int pos = atomicAdd(&cnt[b], 1);
                    if (pos < CAP) l2e[b * CAP + pos] = e;
                }
            }
        }
    }
}

// KB: node table; er dots + h-init; match scan + eager logit dots; block0 writes vl
__global__ __launch_bounds__(256) void kB_match(
        const float* __restrict__ x, const float* __restrict__ ef,
        const int* __restrict__ src, const int* __restrict__ dst,
        const int* __restrict__ goff, const int* __restrict__ l2e,
        const int* __restrict__ cnt, const float* __restrict__ b1,
        const float* __restrict__ v, int E, int B, int nslot,
        int* mcnt, int* medge, int* msrc, float* melog, float* erj, float* h,
        int* vlg, int* vnp) {
    __shared__ int tnode[NSLOTMAX], tslot[NSLOTMAX];
    __shared__ int tn, qn;
    __shared__ int qe[QCAP], qs[QCAP], qsl[QCAP], qp[QCAP];
    int tid = threadIdx.x;
    if (tid == 0) { tn = 0; qn = 0; }
    __syncthreads();
    for (int s = tid; s < nslot; s += 256) {
        int node = -1; bool valid = false;
        if (s < B) { node = goff[s]; valid = true; }
        else { int rb = (s - B) >> 6, i = (s - B) & 63;
               int cb = cnt[rb]; if (cb > CAP) cb = CAP;
               if (i < cb) { node = src[l2e[rb * CAP + i]]; valid = true; } }
        if (valid) { int p = atomicAdd(&tn, 1); tnode[p] = node; tslot[p] = s; }
    }
    __syncthreads();
    int M = tn;
    const float* val1 = v;
    const float* var1 = v + D;
    const float* vae1 = v + 2 * D;
    int wv = tid >> 6, lane = tid & 63;
    // er dot + h init (one wave per slot)
    {
        int s = blockIdx.x * 4 + wv;
        if (s < nslot) {
            int j = -1; bool valid = false;
            if (s < B) { j = goff[s]; valid = true; }
            else { int rb = (s - B) >> 6, i = (s - B) & 63;
                   int cb = cnt[rb]; if (cb > CAP) cb = CAP;
                   if (i < cb) { j = src[l2e[rb * CAP + i]]; valid = true; } }
            if (valid) {
                float acc = 0.f;
                for (int c = lane; c < D; c += 64) acc += x[(long)j * D + c] * var1[c];
                acc = wave_reduce(acc);
                if (lane == 0) erj[s] = acc;
                for (int c = lane; c < D; c += 64)
                    h[(long)s * D + c] = x[(long)j * D + c] + b1[c];
            }
        }
    }
    // edge scan: append matches, queue eager dots
    for (int e = blockIdx.x * 256 + tid; e < E; e += gridDim.x * 256) {
        int d = dst[e];
        for (int c = 0; c < M; ++c) {
            if (tnode[c] == d) {
                int sl = tslot[c];
                int p = atomicAdd(&mcnt[sl], 1);
                if (p < MD1) {
                    int sr = src[e];
                    medge[sl * MD1 + p] = e;
                    msrc[sl * MD1 + p] = sr;
                    int qq = atomicAdd(&qn, 1);
                    if (qq < QCAP) { qe[qq] = e; qs[qq] = sr; qsl[qq] = sl; qp[qq] = p; }
                    else {  // rare overflow: serial dot, same value
                        float acc = 0.f;
                        for (int cc = 0; cc < D; ++cc)
                            acc += x[(long)sr * D + cc] * val1[cc] + ef[(long)e * D + cc] * vae1[cc];
                        melog[sl * MD1 + p] = acc;
                    }
                }
            }
        }
    }
    __syncthreads();
    int nq = qn; if (nq > QCAP) nq = QCAP;
    for (int m = wv; m < nq; m += 4) {
        int e = qe[m], sr = qs[m];
        float acc = 0.f;
        for (int c = lane; c < D; c += 64)
            acc += x[(long)sr * D + c] * val1[c] + ef[(long)e * D + c] * vae1[c];
        acc = wave_reduce(acc);
        if (lane == 0) melog[qsl[m] * MD1 + qp[m]] = acc;
    }
    // canonical valid-row list (deterministic ballot order), block 0 wave 0
    if (blockIdx.x == 0 && tid < 64) {
        int base = 0;
        for (int s0 = 0; s0 < nslot; s0 += 64) {
            int s = s0 + tid;
            bool valid = false;
            if (s < B) valid = true;
            else if (s < nslot) {
                int rb = (s - B) >> 6, i = (s - B) & 63;
                int cb = cnt[rb]; if (cb > CAP) cb = CAP;
                valid = i < cb;
            }
            unsigned long long mb = __ballot(valid);
            if (valid) {
                int ci = base + __popcll(mb & ((1ULL << tid) - 1));
                if (ci < VROWS) vlg[ci] = s;
            }
            base += __popcll(mb);
        }
        if (tid == 0) *vnp = base < VROWS ? base : VROWS;
    }
}

// KC: layer-1 GEMM; 2-way row split (144 blocks); single-pass stage; atomic h
__global__ __launch_bounds__(256) void kC_gemm1(
        const float* __restrict__ W1, const float* __restrict__ We1,
        const float* __restrict__ x, const float* __restrict__ ef,
        const int* __restrict__ mcnt, const int* __restrict__ medge,
        const int* __restrict__ msrc, const float* __restrict__ melog,
        const float* __restrict__ erj, const int* __restrict__ vlg,
        const int* __restrict__ vnp, float* h) {
    int tid = threadIdx.x;
    int q = blockIdx.x % 3, iy = (blockIdx.x / 3) % NI, rh = blockIdx.x / (3 * NI);
    int col = q * 256 + tid, i0 = iy * IC;
    __shared__ int vl_s[VROWS];
    __shared__ int vn_s, snm[32];
    __shared__ float smatt[32][MD1];
    __shared__ int ssrc[32][MD1], sedge[32][MD1];
    __shared__ float sgS[32][IC], sgE[32][IC];
    if (tid == 0) vn_s = *vnp;
    if (tid < VROWS) vl_s[tid] = vlg[tid];
    __syncthreads();
    int vn = vn_s;
    int half = (vn + 1) >> 1;
    int r0 = rh * half, r1 = r0 + half; if (r1 > vn) r1 = vn;
    int nr = r1 - r0;
    if (tid < nr) {  // per own row: load, sort by edge id, leaky+softmax
        int s = vl_s[r0 + tid];
        int nm = mcnt[s]; if (nm > MD1) nm = MD1;
        snm[tid] = nm;
        for (int k = 0; k < nm; ++k) {
            sedge[tid][k] = medge[s * MD1 + k];
            ssrc[tid][k]  = msrc[s * MD1 + k];
            smatt[tid][k] = melog[s * MD1 + k];
        }
        for (int a_ = 1; a_ < nm; ++a_) {
            int ke = sedge[tid][a_], ks = ssrc[tid][a_]; float kl = smatt[tid][a_];
            int b = a_ - 1;
            while (b >= 0 && sedge[tid][b] > ke) {
                sedge[tid][b+1] = sedge[tid][b]; ssrc[tid][b+1] = ssrc[tid][b];
                smatt[tid][b+1] = smatt[tid][b]; --b;
            }
            sedge[tid][b+1] = ke; ssrc[tid][b+1] = ks; smatt[tid][b+1] = kl;
        }
        float er = erj[s], mx = -1e30f;
        for (int k = 0; k < nm; ++k) {
            float l = smatt[tid][k] + er;
            l = l >= 0.f ? l : NEG * l;
            smatt[tid][k] = l; mx = fmaxf(mx, l);
        }
        float sum = 0.f;
        for (int k = 0; k < nm; ++k) { float p = expf(smatt[tid][k] - mx); smatt[tid][k] = p; sum += p; }
        float inv = 1.f / sum;
        for (int k = 0; k < nm; ++k) smatt[tid][k] *= inv;
    }
    __syncthreads();
    // single-pass stage: task t = (local row, mat); 2*nr <= 64 <= 256 threads
    if (tid < 2 * nr) {
        int lr = tid >> 1, mat = tid & 1;
        int nm = snm[lr];
        float acc[IC];
        #pragma unroll
        for (int i = 0; i < IC; ++i) acc[i] = 0.f;
        if (mat == 0) {
            for (int k = 0; k < nm; ++k) {
                const float* p = x + (long)ssrc[lr][k] * D + i0;
                float w_ = smatt[lr][k];
                #pragma unroll
                for (int i = 0; i < IC; ++i) acc[i] += w_ * p[i];
            }
            #pragma unroll
            for (int i = 0; i < IC; ++i) sgS[lr][i] = acc[i];
        } else {
            for (int k = 0; k < nm; ++k) {
                const float* p = ef + (long)sedge[lr][k] * D + i0;
                float w_ = smatt[lr][k];
                #pragma unroll
                for (int i = 0; i < IC; ++i) acc[i] += w_ * p[i];
            }
            #pragma unroll
            for (int i = 0; i < IC; ++i) sgE[lr][i] = acc[i];
        }
    }
    __syncthreads();
    if (nr > 0) {
        float w[IC], we[IC];
        #pragma unroll
        for (int k = 0; k < IC; ++k) {
            w[k]  = W1[(long)(i0 + k) * D + col];
            we[k] = We1[(long)(i0 + k) * D + col];
        }
        for (int lr = 0; lr < nr; ++lr) {
            float acc = 0.f;
            #pragma unroll
            for (int k = 0; k < IC; ++k) acc += sgS[lr][k] * w[k] + sgE[lr][k] * we[k];
            atomicAdd(&h[(long)vl_s[r0 + lr] * D + col], acc);
        }
    }
}

// KD: layer-2 logit dots on relu(h) + er2 + out-init (wave per task)
__global__ __launch_bounds__(256) void kD_l2prep(
        const float* __restrict__ ef, const int* __restrict__ l2e,
        const int* __restrict__ cnt, const float* __restrict__ b2,
        const float* __restrict__ v, const float* __restrict__ h,
        float* elog2, float* er2, float* out, int B, int nslot) {
    int wv = threadIdx.x >> 6, lane = threadIdx.x & 63;
    int t = blockIdx.x * 4 + wv;
    const float* val2 = v + 3 * D;
    const float* var2 = v + 4 * D;
    const float* vae2 = v + 5 * D;
    if (t < B) {
        float acc = 0.f;
        for (int c = lane; c < D; c += 64) acc += fmaxf(h[(long)t * D + c], 0.f) * var2[c];
        acc = wave_reduce(acc);
        if (lane == 0) er2[t] = acc;
        for (int c = lane; c < D; c += 64)
            out[(long)t * D + c] = fmaxf(h[(long)t * D + c], 0.f) + b2[c];
    } else if (t < nslot) {
        int rb = (t - B) >> 6, i = (t - B) & 63;
        int cb = cnt[rb]; if (cb > CAP) cb = CAP;
        if (i < cb) {
            int e = l2e[rb * CAP + i];
            const float* hs = h + (long)t * D;
            float acc = 0.f;
            for (int c = lane; c < D; c += 64)
                acc += fmaxf(hs[c], 0.f) * val2[c] + ef[(long)e * D + c] * vae2[c];
            acc = wave_reduce(acc);
            if (lane == 0) elog2[rb * CAP + i] = acc;
        }
    }
}

// KE: layer-2 GEMM; per-block scalar softmax, single-pass stage, atomic out
__global__ __launch_bounds__(256) void kE_gemm2(
        const float* __restrict__ W2, const float* __restrict__ We2,
        const float* __restrict__ ef, const int* __restrict__ l2e,
        const int* __restrict__ cnt, const float* __restrict__ elog2,
        const float* __restrict__ er2, const float* __restrict__ h,
        float* out, int B) {
    __shared__ float smatt[16][CAP];
    __shared__ int sedge[16][CAP], spos[16][CAP], sdeg[16];
    __shared__ float sgS[16][IC], sgE[16][IC];
    int tid = threadIdx.x;
    int q = blockIdx.x % 3, iy = blockIdx.x / 3;
    int col = q * 256 + tid, i0 = iy * IC;
    if (tid < B) {
        int b = tid;
        int deg = cnt[b]; if (deg > CAP) deg = CAP;
        sdeg[b] = deg;
        for (int k = 0; k < deg; ++k) { sedge[b][k] = l2e[b * CAP + k]; spos[b][k] = k; }
        for (int a_ = 1; a_ < deg; ++a_) {
            int ke = sedge[b][a_], kp = spos[b][a_]; int c = a_ - 1;
            while (c >= 0 && sedge[b][c] > ke) {
                sedge[b][c+1] = sedge[b][c]; spos[b][c+1] = spos[b][c]; --c;
            }
            sedge[b][c+1] = ke; spos[b][c+1] = kp;
        }
        float er = er2[b], mx = -1e30f;
        for (int k = 0; k < deg; ++k) {
            float l = elog2[b * CAP + spos[b][k]] + er;
            l = l >= 0.f ? l : NEG * l;
            smatt[b][k] = l; mx = fmaxf(mx, l);
        }
        float sum = 0.f;
        for (int k = 0; k < deg; ++k) { float p = expf(smatt[b][k] - mx); smatt[b][k] = p; sum += p; }
        float inv = sum > 0.f ? 1.f / sum : 0.f;
        for (int k = 0; k < deg; ++k) smatt[b][k] *= inv;
    }
    __syncthreads();
    // single-pass stage: 2*B = 32 tasks <= 256 threads
    if (tid < 2 * B) {
        int r = tid >> 1, mat = tid & 1;
        int deg = sdeg[r];
        float acc[IC];
        #pragma unroll
        for (int i = 0; i < IC; ++i) acc[i] = 0.f;
        if (mat == 0) {
            for (int k = 0; k < deg; ++k) {
                const float* hs = h + (long)(B + r * CAP + spos[r][k]) * D + i0;
                float w_ = smatt[r][k];
                #pragma unroll
                for (int i = 0; i < IC; ++i) acc[i] += w_ * fmaxf(hs[i], 0.f);
            }
            #pragma unroll
            for (int i = 0; i < IC; ++i) sgS[r][i] = acc[i];
        } else {
            for (int k = 0; k < deg; ++k) {
                const float* p = ef + (long)sedge[r][k] * D + i0;
                float w_ = smatt[r][k];
                #pragma unroll
                for (int i = 0; i < IC; ++i) acc[i] += w_ * p[i];
            }
            #pragma unroll
            for (int i = 0; i < IC; ++i) sgE[r][i] = acc[i];
        }
    }
    __syncthreads();
    {
        float w[IC], we[IC];
        #pragma unroll
        for (int k = 0; k < IC; ++k) {
            w[k]  = W2[(long)(i0 + k) * D + col];
            we[k] = We2[(long)(i0 + k) * D + col];
        }
        for (int r = 0; r < B; ++r) {
            float acc = 0.f;
            #pragma unroll
            for (int k = 0; k < IC; ++k) acc += sgS[r][k] * w[k] + sgE[r][k] * we[k];
            atomicAdd(&out[(long)r * D + col], acc);
        }
    }
}

extern "C" void kernel_launch(void* const* d_in, const int* in_sizes, int n_in,
                              void* d_out, int out_size, void* d_ws, size_t ws_size,
                              hipStream_t stream) {
    const float* x    = (const float*)d_in[0];
    const float* ef   = (const float*)d_in[1];
    const int*   src  = (const int*)d_in[2];
    const int*   dst  = (const int*)d_in[3];
    const int*   goff = (const int*)d_in[4];
    const float* W1   = (const float*)d_in[5];
    const float* We1  = (const float*)d_in[6];
    const float* al1  = (const float*)d_in[7];
    const float* ar1  = (const float*)d_in[8];
    const float* ae1  = (const float*)d_in[9];
    const float* b1   = (const float*)d_in[10];
    const float* W2   = (const float*)d_in[11];
    const float* We2  = (const float*)d_in[12];
    const float* al2  = (const float*)d_in[13];
    const float* ar2  = (const float*)d_in[14];
    const float* ae2  = (const float*)d_in[15];
    const float* b2   = (const float*)d_in[16];
    float* out = (float*)d_out;

    int E = in_sizes[2];
    int B = in_sizes[4];
    int nslot = B + B * CAP;   // 1040

    float* ws    = (float*)d_ws;
    float* v     = ws;                            // 6*D
    int*   l2e   = (int*)(v + 6 * D);             // B*CAP
    int*   cnt   = l2e + B * CAP;                 // B      } zeroed by memset
    int*   mcnt  = cnt + B;                       // nslot  }
    int*   medge = mcnt + nslot;                  // nslot*MD1
    int*   msrc  = medge + nslot * MD1;           // nslot*MD1
    float* melog = (float*)(msrc + nslot * MD1);  // nslot*MD1
    float* erj   = melog + nslot * MD1;           // nslot
    int*   vlg   = (int*)(erj + nslot);           // VROWS
    int*   vnp   = vlg + VROWS;                   // 1
    float* elog2 = (float*)(vnp + 1);             // B*CAP
    float* er2   = elog2 + B * CAP;               // B
    float* h     = er2 + B;                       // nslot*D

    int egrid = (E + 255) / 256;

    hipMemsetAsync(cnt, 0, (size_t)(B + nslot) * sizeof(int), stream);
    hipLaunchKernelGGL(kA_proj_build, dim3(NPROJ + egrid), dim3(256), 0, stream,
                       W1, We1, W2, We2, al1, ar1, ae1, al2, ar2, ae2,
                       dst, goff, E, B, v, l2e, cnt);
    hipLaunchKernelGGL(kB_match, dim3(egrid), dim3(256), 0, stream,
                       x, ef, src, dst, goff, l2e, cnt, b1, v, E, B, nslot,
                       mcnt, medge, msrc, melog, erj, h, vlg, vnp);
    hipLaunchKernelGGL(kC_gemm1, dim3(3 * NI * 2), dim3(256), 0, stream,
                       W1, We1, x, ef, mcnt, medge, msrc, melog, erj, vlg, vnp, h);
    hipLaunchKernelGGL(kD_l2prep, dim3((nslot + 3) / 4), dim3(256), 0, stream,
                       ef, l2e, cnt, b2, v, h, elog2, er2, out, B, nslot);
    hipLaunchKernelGGL(kE_gemm2, dim3(3 * NI), dim3(256), 0, stream,
                       W2, We2, ef, l2e, cnt, elog2, er2, h, out, B);
}